// Round 7
// baseline (13119.609 us; speedup 1.0000x reference)
//
#include <hip/hip_runtime.h>

#define T_LEN 2048
#define G_N   24
#define V_N   2048
#define K_N   512
#define NCL   48          // legacy constant (sizes the tag buffer memset)
#define NBLK  48          // 24 groups x 2 column-half WGs; both dirs fused per WG

// ---------------- workspace layout (bytes) ----------------
#define TOK_OFF    4096
#define ROWS_OFF   16384
#define HBUF_OFF   262144     // 24 g x 2 chain x 2 ws x 2 bufs x 256 x 8B = 384 KB
#define P_OFF      786432     // 4 MB

#define LOAD_RLX64(p)     __hip_atomic_load((p), __ATOMIC_RELAXED, __HIP_MEMORY_SCOPE_AGENT)
#define STORE_RLX64(p, v) __hip_atomic_store((p), (v), __ATOMIC_RELAXED, __HIP_MEMORY_SCOPE_AGENT)

// LDS-visibility barrier WITHOUT the __syncthreads vmcnt(0) drain (R6 win):
// lgkmcnt(0) then s_barrier; compiler memory fences pin LDS ops (rule #18).
#define BAR_LDS() do {                                         \
    asm volatile("s_waitcnt lgkmcnt(0)" ::: "memory");         \
    __builtin_amdgcn_s_barrier();                              \
    asm volatile("" ::: "memory");                             \
} while (0)

// ---- phase 0: recover tokens from one-hot rows ----
__global__ void tok_kernel(const float* __restrict__ seq, int* __restrict__ tokens) {
    int wid  = (blockIdx.x * blockDim.x + threadIdx.x) >> 6;
    int lane = threadIdx.x & 63;
    if (wid >= T_LEN) return;
    const float* row = seq + (size_t)wid * V_N;
    for (int i = lane; i < V_N; i += 64) {
        if (row[i] > 0.5f) tokens[wid] = i;
    }
}

// ---- phase 1: rows[g][t] = perms[g][token[t]] ----
__global__ void rows_kernel(const int* __restrict__ tokens, const int* __restrict__ perms,
                            int* __restrict__ rows) {
    int idx = blockIdx.x * blockDim.x + threadIdx.x;
    if (idx >= G_N * T_LEN) return;
    int g = idx / T_LEN, t = idx - g * T_LEN;
    rows[idx] = perms[g * V_N + tokens[t]];
}

// ---- phase 2: P = W_e @ Wx + b ----
__global__ __launch_bounds__(256) void pgemm_kernel(const float* __restrict__ We,
                                                    const float* __restrict__ Wx,
                                                    const float* __restrict__ b,
                                                    float* __restrict__ P) {
    __shared__ float As[16][72];
    __shared__ float Bs[16][68];
    int tid = threadIdx.x;
    int bx = blockIdx.x & 7;
    int by = blockIdx.x >> 3;
    int tx = tid & 15, ty = tid >> 4;
    int v0 = by * 64, j0 = bx * 64;
    float acc[4][4] = {};
    for (int k0 = 0; k0 < K_N; k0 += 16) {
        int ar = tid >> 2;
        int ac = (tid & 3) << 2;
        float4 av = *(const float4*)(We + (size_t)(v0 + ar) * K_N + k0 + ac);
        As[ac + 0][ar] = av.x; As[ac + 1][ar] = av.y;
        As[ac + 2][ar] = av.z; As[ac + 3][ar] = av.w;
        int br = tid >> 4;
        int bc = (tid & 15) << 2;
        float4 bv = *(const float4*)(Wx + (size_t)(k0 + br) * K_N + j0 + bc);
        *(float4*)&Bs[br][bc] = bv;
        __syncthreads();
#pragma unroll
        for (int kk = 0; kk < 16; kk++) {
            float a0 = As[kk][ty * 4 + 0], a1 = As[kk][ty * 4 + 1];
            float a2 = As[kk][ty * 4 + 2], a3 = As[kk][ty * 4 + 3];
            float4 bb = *(const float4*)&Bs[kk][tx * 4];
            acc[0][0] += a0 * bb.x; acc[0][1] += a0 * bb.y; acc[0][2] += a0 * bb.z; acc[0][3] += a0 * bb.w;
            acc[1][0] += a1 * bb.x; acc[1][1] += a1 * bb.y; acc[1][2] += a1 * bb.z; acc[1][3] += a1 * bb.w;
            acc[2][0] += a2 * bb.x; acc[2][1] += a2 * bb.y; acc[2][2] += a2 * bb.z; acc[2][3] += a2 * bb.w;
            acc[3][0] += a3 * bb.x; acc[3][1] += a3 * bb.y; acc[3][2] += a3 * bb.z; acc[3][3] += a3 * bb.w;
        }
        __syncthreads();
    }
    float4 bb = *(const float4*)(b + j0 + tx * 4);
#pragma unroll
    for (int i = 0; i < 4; i++) {
        float4 r;
        r.x = acc[i][0] + bb.x; r.y = acc[i][1] + bb.y;
        r.z = acc[i][2] + bb.z; r.w = acc[i][3] + bb.w;
        *(float4*)(P + (size_t)(v0 + ty * 4 + i) * K_N + j0 + tx * 4) = r;
    }
}

// ---- phase 3: fused-bidirectional 2-WG-per-group RNN ----
// 48 blocks x 512 threads; block = (g, ws). WG ws owns columns
// [256ws, 256ws+256) over ALL 512 k-rows for BOTH directions (fwd+bwd share
// Wh!). Weights identical to R6: 128 KB LDS + 48 float4 regs (compiler
// splits 128 VGPR + AGPR overflow; AGPRs are direct VALU operands, proven
// R4/R6). Each weight read feeds 8 FMAs (2 chains x 4 cols) -> LDS
// pressure per FLOP halves vs R6.
// The two chains' FMA1 phases (~1024 cy wall) fully cover the partner-h
// LLC store->load latency that R6 only half-hid (its tag-retry stalls).
// Thread roles: FMA phases: all 512 threads, (q=tid>>6 wave, c=tid&63)
// compute cols 4c..4c+3 for both chains. Serial phases: chain=tid>>8,
// lc=tid&255 -> thread owns (chain, col lc): xv prefetch, reduce, tanh,
// tagged publish, out store. No idle half anywhere.
// Exchange: R6's tagged 8B {tag=s+1, h bits} relaxed agent-scope protocol,
// per chain. Ping-pong + monotone tags + per-launch memset.
__global__ __attribute__((amdgpu_flat_work_group_size(512, 512), amdgpu_waves_per_eu(2, 2)))
void rnn_bidi(const float* __restrict__ P, const float* __restrict__ Wh,
              const int* __restrict__ rows, unsigned long long* __restrict__ h_buf,
              float* __restrict__ out) {

    __shared__ __align__(16) float  lds_h[2 * K_N];      // 4 KB: [chain][512]
    __shared__ __align__(16) float4 Wlds[16 * 512];      // 128 KB: [ph*8+row][tid]
    __shared__ __align__(16) float  pr[16 * 264];        // 16.5 KB: [chain*8+q][col]

    const int tid = threadIdx.x;
    const int q   = tid >> 6;          // wave id: k-subslice (32 own + 32 partner rows)
    const int c   = tid & 63;          // col group: local cols 4c..4c+3
    const int g   = blockIdx.x >> 1;
    const int ws  = blockIdx.x & 1;    // column half
    const int chain = tid >> 8;        // this thread's serial-phase chain (0 fwd, 1 bwd)
    const int lc    = tid & 255;       // this thread's serial-phase column

    const int ownbase = ws << 8;             // my 256 columns AND "my" k-half
    const int pbase   = ownbase ^ 256;       // partner half
    const int wcol    = (ws << 6) + c;       // f4 column index into Wh row

    const float4* __restrict__ Wh4 = (const float4*)Wh;

    // weight fill (identical to R6): ph0 = own-half k rows, ph1 = partner-half.
    // rows 0..7 of each 32-row slice -> LDS, rows 8..31 -> registers/AGPRs.
    float4 Wreg[48];
#pragma unroll
    for (int ph = 0; ph < 2; ph++) {
        const int kb = (ph == 0 ? ownbase : pbase) + (q << 5);
#pragma unroll
        for (int i = 0; i < 32; i++) {
            float4 w = Wh4[(size_t)(kb + i) * 128 + wcol];
            if (i < 8) Wlds[(ph * 8 + i) * 512 + tid] = w;
            else       Wreg[ph * 24 + (i - 8)] = w;
        }
    }
    lds_h[tid] = 0.f;                        // h_0 = 0, both chains
    lds_h[512 + tid] = 0.f;

    const int* __restrict__ myrows = rows + g * T_LEN;
    int t0 = (chain == 0) ? 0 : (T_LEN - 2);
    float xv = P[(size_t)myrows[t0] * K_N + ownbase + lc];
    int t1 = (chain == 0) ? 1 : (T_LEN - 3);
    int rnxt = myrows[t1];

    unsigned long long* hbme = h_buf + ((size_t)(g * 2 + chain) * 2 + ws) * 512;
    unsigned long long* hbpt = h_buf + ((size_t)(g * 2 + chain) * 2 + (ws ^ 1)) * 512;

    const size_t outbase = (size_t)g * 1024 + (size_t)chain * 512 + ownbase + lc;
    float h_prev = 0.f;
    size_t prev_addr = 0;

    __syncthreads();   // one-time: weights + h0 visible (full drain OK here)

    for (int s = 0; s < T_LEN; s++) {
        // ---- issue partner-h tagged load FIRST (resolves after FMA1) ----
        unsigned long long pvbits = 0;
        if (s > 0)
            pvbits = LOAD_RLX64(&hbpt[((s - 1) & 1) * 256 + lc]);

        // staggered out-store of h(s-1): fire-and-forget
        if (s > 0) __builtin_nontemporal_store(h_prev, &out[prev_addr]);
        // x prefetch for s+1; row index for s+2 (per-chain formula)
        float xv_next = 0.f;
        if (s + 1 < T_LEN) xv_next = P[(size_t)rnxt * K_N + ownbase + lc];
        if (s + 2 < T_LEN) {
            int sn = s + 2;
            int tn = (chain == 0) ? sn : ((sn == T_LEN - 1) ? (T_LEN - 1) : (T_LEN - 2 - sn));
            rnxt = myrows[tn];
        }

        const float4* __restrict__ h4f = (const float4*)lds_h;
        const float4* __restrict__ h4b = (const float4*)(lds_h + 512);
        float4 af = {0.f, 0.f, 0.f, 0.f}, ab = {0.f, 0.f, 0.f, 0.f};

        // ---- FMA1: 32 own-half rows, BOTH chains (one weight -> 8 FMAs) ----
        {
            const int hb = (ownbase >> 2) + (q << 3);
#pragma unroll
            for (int r8 = 0; r8 < 8; r8++) {
                float4 hf = h4f[hb + r8];                // uniform -> broadcast
                float4 hbv = h4b[hb + r8];
#pragma unroll
                for (int e = 0; e < 4; e++) {
                    float sf = (e == 0) ? hf.x : (e == 1) ? hf.y : (e == 2) ? hf.z : hf.w;
                    float sb = (e == 0) ? hbv.x : (e == 1) ? hbv.y : (e == 2) ? hbv.z : hbv.w;
                    const int i = 4 * r8 + e;
                    float4 w = (i < 8) ? Wlds[i * 512 + tid] : Wreg[i - 8];
                    af.x += sf * w.x; af.y += sf * w.y; af.z += sf * w.z; af.w += sf * w.w;
                    ab.x += sb * w.x; ab.y += sb * w.y; ab.z += sb * w.z; ab.w += sb * w.w;
                }
            }
        }
        // ---- resolve partner h (own chain role); latency fully hidden ----
        if (s > 0) {
            while ((unsigned)(pvbits >> 32) != (unsigned)s)
                pvbits = LOAD_RLX64(&hbpt[((s - 1) & 1) * 256 + lc]);
            lds_h[chain * 512 + pbase + lc] = __uint_as_float((unsigned)pvbits);
        }
        BAR_LDS();                                     // A: partner halves visible

        // ---- FMA2: 32 partner-half rows, both chains ----
        {
            const int hb = (pbase >> 2) + (q << 3);
#pragma unroll
            for (int r8 = 0; r8 < 8; r8++) {
                float4 hf = h4f[hb + r8];
                float4 hbv = h4b[hb + r8];
#pragma unroll
                for (int e = 0; e < 4; e++) {
                    float sf = (e == 0) ? hf.x : (e == 1) ? hf.y : (e == 2) ? hf.z : hf.w;
                    float sb = (e == 0) ? hbv.x : (e == 1) ? hbv.y : (e == 2) ? hbv.z : hbv.w;
                    const int i = 4 * r8 + e;
                    float4 w = (i < 8) ? Wlds[(8 + i) * 512 + tid] : Wreg[24 + i - 8];
                    af.x += sf * w.x; af.y += sf * w.y; af.z += sf * w.z; af.w += sf * w.w;
                    ab.x += sb * w.x; ab.y += sb * w.y; ab.z += sb * w.z; ab.w += sb * w.w;
                }
            }
        }
        *(float4*)&pr[q * 264 + 4 * c] = af;           // chain-0 partials
        *(float4*)&pr[(8 + q) * 264 + 4 * c] = ab;     // chain-1 partials
        BAR_LDS();                                     // B: partials visible

        // ---- reduce own (chain, col lc); all 512 threads productive ----
        {
            const float* prc = pr + chain * 8 * 264;
            float p0 = prc[0 * 264 + lc], p1 = prc[1 * 264 + lc];
            float p2 = prc[2 * 264 + lc], p3 = prc[3 * 264 + lc];
            float p4 = prc[4 * 264 + lc], p5 = prc[5 * 264 + lc];
            float p6 = prc[6 * 264 + lc], p7 = prc[7 * 264 + lc];
            float sum = ((p0 + p1) + (p2 + p3)) + ((p4 + p5) + (p6 + p7));
            float z = xv + sum;
            z = fminf(15.f, fmaxf(-15.f, z));
            float e2 = __expf(2.f * z);
            float h1 = 1.f - 2.f / (e2 + 1.f);         // tanh(z)
            xv = xv_next;

            int tphys = (chain == 0) ? s : ((s == T_LEN - 1) ? (T_LEN - 1) : (T_LEN - 2 - s));
            prev_addr = (size_t)tphys * (G_N * 1024) + outbase;
            h_prev = h1;
            if (s < T_LEN - 1) {
                unsigned long long pk =
                    ((unsigned long long)(unsigned)(s + 1) << 32) | __float_as_uint(h1);
                STORE_RLX64(&hbme[(s & 1) * 256 + lc], pk);   // store IS the signal
                lds_h[chain * 512 + ownbase + lc] = h1;       // own half stays local
            }
        }
        if (s == T_LEN - 1) break;
        BAR_LDS();                                     // C: own-half h visible
    }
    __builtin_nontemporal_store(h_prev, &out[prev_addr]);
    __builtin_nontemporal_store(h_prev, &out[(size_t)T_LEN * (G_N * 1024) + outbase]);
}

extern "C" void kernel_launch(void* const* d_in, const int* in_sizes, int n_in,
                              void* d_out, int out_size, void* d_ws, size_t ws_size,
                              hipStream_t stream) {
    const float* seq   = (const float*)d_in[0];
    const int*   perms = (const int*)d_in[1];
    const float* We    = (const float*)d_in[2];
    const float* Wx    = (const float*)d_in[3];
    const float* Wh    = (const float*)d_in[4];
    const float* b     = (const float*)d_in[5];
    float* out = (float*)d_out;
    char* ws = (char*)d_ws;

    int*   tokens = (int*)(ws + TOK_OFF);
    int*   rows   = (int*)(ws + ROWS_OFF);
    unsigned long long* hbuf = (unsigned long long*)(ws + HBUF_OFF);
    float* P      = (float*)(ws + P_OFF);

    // zero the tag buffer each launch: stale tags must never match (tags start at 1)
    (void)hipMemsetAsync(hbuf, 0, NCL * 2 * 2 * 256 * sizeof(unsigned long long), stream);
    tok_kernel<<<512, 256, 0, stream>>>(seq, tokens);
    rows_kernel<<<(G_N * T_LEN + 255) / 256, 256, 0, stream>>>(tokens, perms, rows);
    pgemm_kernel<<<256, 256, 0, stream>>>(We, Wx, b, P);
    rnn_bidi<<<NBLK, 512, 0, stream>>>(P, Wh, rows, hbuf, out);
}

// Round 8
// 5191.814 us; speedup vs baseline: 2.5270x; 2.5270x over previous
//
#include <hip/hip_runtime.h>

#define T_LEN 2048
#define G_N   24
#define V_N   2048
#define K_N   512
#define NBLK  96          // 24 groups x 4 quadrant-WGs (both dirs fused per WG)

// ---------------- workspace layout (bytes) ----------------
#define TOK_OFF    4096
#define ROWS_OFF   16384
#define HBUF_OFF   262144     // 24g x 2d x 2rb x 2cb x 2pp x 256 x 8B = 786432 B
#define P_OFF      1048576    // 4 MB

#define LOAD_RLX64(p)     __hip_atomic_load((p), __ATOMIC_RELAXED, __HIP_MEMORY_SCOPE_AGENT)
#define STORE_RLX64(p, v) __hip_atomic_store((p), (v), __ATOMIC_RELAXED, __HIP_MEMORY_SCOPE_AGENT)

// LDS-visibility barrier WITHOUT the __syncthreads vmcnt(0) drain (R6 win)
#define BAR_LDS() do {                                         \
    asm volatile("s_waitcnt lgkmcnt(0)" ::: "memory");         \
    __builtin_amdgcn_s_barrier();                              \
    asm volatile("" ::: "memory");                             \
} while (0)

// ---- phase 0: recover tokens from one-hot rows ----
__global__ void tok_kernel(const float* __restrict__ seq, int* __restrict__ tokens) {
    int wid  = (blockIdx.x * blockDim.x + threadIdx.x) >> 6;
    int lane = threadIdx.x & 63;
    if (wid >= T_LEN) return;
    const float* row = seq + (size_t)wid * V_N;
    for (int i = lane; i < V_N; i += 64) {
        if (row[i] > 0.5f) tokens[wid] = i;
    }
}

// ---- phase 1: rows[g][t] = perms[g][token[t]] ----
__global__ void rows_kernel(const int* __restrict__ tokens, const int* __restrict__ perms,
                            int* __restrict__ rows) {
    int idx = blockIdx.x * blockDim.x + threadIdx.x;
    if (idx >= G_N * T_LEN) return;
    int g = idx / T_LEN, t = idx - g * T_LEN;
    rows[idx] = perms[g * V_N + tokens[t]];
}

// ---- phase 2: P = W_e @ Wx + b ----
__global__ __launch_bounds__(256) void pgemm_kernel(const float* __restrict__ We,
                                                    const float* __restrict__ Wx,
                                                    const float* __restrict__ b,
                                                    float* __restrict__ P) {
    __shared__ float As[16][72];
    __shared__ float Bs[16][68];
    int tid = threadIdx.x;
    int bx = blockIdx.x & 7;
    int by = blockIdx.x >> 3;
    int tx = tid & 15, ty = tid >> 4;
    int v0 = by * 64, j0 = bx * 64;
    float acc[4][4] = {};
    for (int k0 = 0; k0 < K_N; k0 += 16) {
        int ar = tid >> 2;
        int ac = (tid & 3) << 2;
        float4 av = *(const float4*)(We + (size_t)(v0 + ar) * K_N + k0 + ac);
        As[ac + 0][ar] = av.x; As[ac + 1][ar] = av.y;
        As[ac + 2][ar] = av.z; As[ac + 3][ar] = av.w;
        int br = tid >> 4;
        int bc = (tid & 15) << 2;
        float4 bv = *(const float4*)(Wx + (size_t)(k0 + br) * K_N + j0 + bc);
        *(float4*)&Bs[br][bc] = bv;
        __syncthreads();
#pragma unroll
        for (int kk = 0; kk < 16; kk++) {
            float a0 = As[kk][ty * 4 + 0], a1 = As[kk][ty * 4 + 1];
            float a2 = As[kk][ty * 4 + 2], a3 = As[kk][ty * 4 + 3];
            float4 bb = *(const float4*)&Bs[kk][tx * 4];
            acc[0][0] += a0 * bb.x; acc[0][1] += a0 * bb.y; acc[0][2] += a0 * bb.z; acc[0][3] += a0 * bb.w;
            acc[1][0] += a1 * bb.x; acc[1][1] += a1 * bb.y; acc[1][2] += a1 * bb.z; acc[1][3] += a1 * bb.w;
            acc[2][0] += a2 * bb.x; acc[2][1] += a2 * bb.y; acc[2][2] += a2 * bb.z; acc[2][3] += a2 * bb.w;
            acc[3][0] += a3 * bb.x; acc[3][1] += a3 * bb.y; acc[3][2] += a3 * bb.z; acc[3][3] += a3 * bb.w;
        }
        __syncthreads();
    }
    float4 bb = *(const float4*)(b + j0 + tx * 4);
#pragma unroll
    for (int i = 0; i < 4; i++) {
        float4 r;
        r.x = acc[i][0] + bb.x; r.y = acc[i][1] + bb.y;
        r.z = acc[i][2] + bb.z; r.w = acc[i][3] + bb.w;
        *(float4*)(P + (size_t)(v0 + ty * 4 + i) * K_N + j0 + tx * 4) = r;
    }
}

// ---- phase 3: quadrant-split RNN, weights 100% in registers ----
// 96 blocks x 512 threads; block = (g, RB, CB). WG owns the 256x256 Wh
// quadrant rows [256RB,+256) x cols [256CB,+256) = 32 float4/thread = 128
// regs -> ZERO per-lane-distinct LDS weight reads per step (R6's dominant
// measured cost, ~128 KB/CU/step through the 128 B/cy LDS pipe). The only
// LDS reads left are wave-uniform h broadcasts (cheap) + the small pr
// reduce. Both dirs computed in the same WG from the SAME weight registers
// (Wh shared across dirs): adds only FMA issue, no extra latency phase.
// Per step: FMA both dirs -> barrier -> intra-WG 8-wave reduce -> tagged
// 8B publish of the quadrant partial (store IS the signal, R6 protocol) ->
// read 3 partner partials (one LLC RT, the only exposed latency) -> every
// WG redundantly assembles FULL h -> tanh -> lds_h -> barrier. 2 barriers,
// 1 RT, no weight traffic.
__global__ __attribute__((amdgpu_flat_work_group_size(512, 512), amdgpu_waves_per_eu(2, 2)))
void rnn_quad(const float* __restrict__ P, const float* __restrict__ Wh,
              const int* __restrict__ rows, unsigned long long* __restrict__ h_buf,
              float* __restrict__ out) {

    __shared__ __align__(16) float lds_h[2][512];        // 4 KB: [dir][col]
    __shared__ __align__(16) float pr[2][8][264];        // 16.9 KB padded

    const int tid = threadIdx.x;
    const int fc  = tid & 63;          // f4-col within quadrant (cols 4fc..4fc+3)
    const int kq  = tid >> 6;          // wave id: 32-row slice of the quadrant
    const int g   = blockIdx.x >> 2;
    const int RB  = (blockIdx.x >> 1) & 1;   // row-block of quadrant
    const int CB  = blockIdx.x & 1;          // col-block of quadrant
    const int d_r = tid >> 8;          // resolver dir (0 fwd, 1 bwd)
    const int lc  = tid & 255;         // resolver local col

    // ---- one-time: quadrant weights -> registers (coalesced f4 loads) ----
    const float4* __restrict__ Wh4 = (const float4*)Wh;
    const int rowbase = (RB << 8) + (kq << 5);
    float4 Wreg[32];
#pragma unroll
    for (int i = 0; i < 32; i++)
        Wreg[i] = Wh4[(size_t)(rowbase + i) * 128 + (CB << 6) + fc];

    lds_h[0][tid] = 0.f;               // h_0 = 0, both dirs
    lds_h[1][tid] = 0.f;

    const int* __restrict__ myrows = rows + g * T_LEN;
    int t0 = (d_r == 0) ? 0 : (T_LEN - 2);
    float xv0 = P[(size_t)myrows[t0] * K_N + lc];
    float xv1 = P[(size_t)myrows[t0] * K_N + lc + 256];
    int t1 = (d_r == 0) ? 1 : (T_LEN - 3);
    int rnxt = myrows[t1];

    // partial buffers: [g][d][rb][cb][pp][col], 8B tagged entries
#define BUF(dd, rb, cb) (h_buf + ((((size_t)g * 2 + (dd)) * 2 + (rb)) * 2 + (cb)) * 2 * 256)
    unsigned long long* bown = BUF(d_r, RB, CB);
    unsigned long long* brem0 = BUF(d_r, RB ^ 1, CB);       // other rb, own cb
    unsigned long long* brem1 = BUF(d_r, 0, CB ^ 1);        // rb0, other cb
    unsigned long long* brem2 = BUF(d_r, 1, CB ^ 1);        // rb1, other cb

    const int writer = (d_r == RB);    // WG (RB,CB) writes out dir RB, colhalf CB
    const size_t outbase = (size_t)g * 1024 + (size_t)RB * 512 + (CB << 8) + lc;
    float h_prev = 0.f;
    size_t prev_addr = 0;

    __syncthreads();   // one-time full drain: weights + h0 visible

    for (int s = 0; s < T_LEN; s++) {
        // staggered out-store of h(s-1): fire-and-forget under this step
        if (s > 0 && writer) __builtin_nontemporal_store(h_prev, &out[prev_addr]);
        // x prefetch for s+1; row index for s+2 (per resolver dir)
        float xn0 = 0.f, xn1 = 0.f;
        if (s + 1 < T_LEN) {
            xn0 = P[(size_t)rnxt * K_N + lc];
            xn1 = P[(size_t)rnxt * K_N + lc + 256];
        }
        if (s + 2 < T_LEN) {
            int sn = s + 2;
            int tn = (d_r == 0) ? sn : ((sn == T_LEN - 1) ? (T_LEN - 1) : (T_LEN - 2 - sn));
            rnxt = myrows[tn];
        }

        // ---- FMA: 32 quadrant rows x 4 cols, BOTH dirs, reg weights only ----
        const float4* __restrict__ lh4 = (const float4*)lds_h;
        const int hb = (RB << 6) + (kq << 3);              // f4 index, wave-uniform
        float4 af = {0.f, 0.f, 0.f, 0.f}, ab = {0.f, 0.f, 0.f, 0.f};
#pragma unroll
        for (int r8 = 0; r8 < 8; r8++) {
            float4 hf = lh4[hb + r8];                      // dir0 h, broadcast
            float4 hv = lh4[128 + hb + r8];                // dir1 h, broadcast
#pragma unroll
            for (int e = 0; e < 4; e++) {
                float sf = (e == 0) ? hf.x : (e == 1) ? hf.y : (e == 2) ? hf.z : hf.w;
                float sb = (e == 0) ? hv.x : (e == 1) ? hv.y : (e == 2) ? hv.z : hv.w;
                float4 w = Wreg[4 * r8 + e];
                af.x += sf * w.x; af.y += sf * w.y; af.z += sf * w.z; af.w += sf * w.w;
                ab.x += sb * w.x; ab.y += sb * w.y; ab.z += sb * w.z; ab.w += sb * w.w;
            }
        }
        *(float4*)&pr[0][kq][4 * fc] = af;                 // 16B-stride, conflict-free
        *(float4*)&pr[1][kq][4 * fc] = ab;
        BAR_LDS();                                         // A: partials visible

        // ---- intra-WG reduce for (d_r, lc); publish tagged quadrant partial ----
        float p0 = pr[d_r][0][lc], p1 = pr[d_r][1][lc];
        float p2 = pr[d_r][2][lc], p3 = pr[d_r][3][lc];
        float p4 = pr[d_r][4][lc], p5 = pr[d_r][5][lc];
        float p6 = pr[d_r][6][lc], p7 = pr[d_r][7][lc];
        float own_p = ((p0 + p1) + (p2 + p3)) + ((p4 + p5) + (p6 + p7));
        {
            unsigned long long pk =
                ((unsigned long long)(unsigned)(s + 1) << 32) | __float_as_uint(own_p);
            STORE_RLX64(&bown[(s & 1) * 256 + lc], pk);    // store IS the signal
        }

        // ---- resolve 3 partner partials (the one exposed LLC RT) ----
        unsigned long long e0 = LOAD_RLX64(&brem0[(s & 1) * 256 + lc]);
        unsigned long long e1 = LOAD_RLX64(&brem1[(s & 1) * 256 + lc]);
        unsigned long long e2 = LOAD_RLX64(&brem2[(s & 1) * 256 + lc]);
        while ((unsigned)(e0 >> 32) != (unsigned)(s + 1))
            e0 = LOAD_RLX64(&brem0[(s & 1) * 256 + lc]);
        while ((unsigned)(e1 >> 32) != (unsigned)(s + 1))
            e1 = LOAD_RLX64(&brem1[(s & 1) * 256 + lc]);
        while ((unsigned)(e2 >> 32) != (unsigned)(s + 1))
            e2 = LOAD_RLX64(&brem2[(s & 1) * 256 + lc]);
        float r0 = __uint_as_float((unsigned)e0);          // (RB^1, CB)
        float r1 = __uint_as_float((unsigned)e1);          // (0, CB^1)
        float r2 = __uint_as_float((unsigned)e2);          // (1, CB^1)

        // assemble both col-halves of h[d_r]: col0 = lc (cb=0), col1 = lc+256 (cb=1)
        float c0a, c0b, c1a, c1b;                          // (rb0, rb1) per col-half
        if (CB == 0) {
            c0a = (RB == 0) ? own_p : r0;  c0b = (RB == 0) ? r0 : own_p;
            c1a = r1;                      c1b = r2;
        } else {
            c1a = (RB == 0) ? own_p : r0;  c1b = (RB == 0) ? r0 : own_p;
            c0a = r1;                      c0b = r2;
        }
        float z0 = xv0 + (c0a + c0b);
        z0 = fminf(15.f, fmaxf(-15.f, z0));
        float ee0 = __expf(2.f * z0);
        float h0 = 1.f - 2.f / (ee0 + 1.f);                // tanh
        float z1 = xv1 + (c1a + c1b);
        z1 = fminf(15.f, fmaxf(-15.f, z1));
        float ee1 = __expf(2.f * z1);
        float h1 = 1.f - 2.f / (ee1 + 1.f);
        xv0 = xn0; xv1 = xn1;

        lds_h[d_r][lc] = h0;                               // full h assembled locally
        lds_h[d_r][lc + 256] = h1;

        if (writer) {
            int tphys = (d_r == 0) ? s : ((s == T_LEN - 1) ? (T_LEN - 1) : (T_LEN - 2 - s));
            prev_addr = (size_t)tphys * (G_N * 1024) + outbase;
            h_prev = (CB == 0) ? h0 : h1;
        }
        if (s == T_LEN - 1) break;
        BAR_LDS();                                         // B: h_s visible for next FMA
    }
    if (writer) {
        __builtin_nontemporal_store(h_prev, &out[prev_addr]);
        __builtin_nontemporal_store(h_prev, &out[(size_t)T_LEN * (G_N * 1024) + outbase]);
    }
}

extern "C" void kernel_launch(void* const* d_in, const int* in_sizes, int n_in,
                              void* d_out, int out_size, void* d_ws, size_t ws_size,
                              hipStream_t stream) {
    const float* seq   = (const float*)d_in[0];
    const int*   perms = (const int*)d_in[1];
    const float* We    = (const float*)d_in[2];
    const float* Wx    = (const float*)d_in[3];
    const float* Wh    = (const float*)d_in[4];
    const float* b     = (const float*)d_in[5];
    float* out = (float*)d_out;
    char* ws = (char*)d_ws;

    int*   tokens = (int*)(ws + TOK_OFF);
    int*   rows   = (int*)(ws + ROWS_OFF);
    unsigned long long* hbuf = (unsigned long long*)(ws + HBUF_OFF);
    float* P      = (float*)(ws + P_OFF);

    // zero the tag buffer each launch: stale tags must never match (tags start at 1)
    (void)hipMemsetAsync(hbuf, 0, (size_t)G_N * 2 * 2 * 2 * 2 * 256 * sizeof(unsigned long long), stream);
    tok_kernel<<<512, 256, 0, stream>>>(seq, tokens);
    rows_kernel<<<(G_N * T_LEN + 255) / 256, 256, 0, stream>>>(tokens, perms, rows);
    pgemm_kernel<<<256, 256, 0, stream>>>(We, Wx, b, P);
    rnn_quad<<<NBLK, 512, 0, stream>>>(P, Wh, rows, hbuf, out);
}